// Round 1
// baseline (712.747 us; speedup 1.0000x reference)
//
#include <hip/hip_runtime.h>
#include <cstdint>

// SpikeModel: 3-layer stride-2 3x3 spiking CNN, T=20, bs=32.
// Decomposition: layers are separable over the full time horizon
// (layer i at time t only needs layer i-1 spikes at time t), so:
//   k1: conv1 over all t, pot1 in registers, spikes -> bitpacked ws
//   k2: conv2 over all t, reads spk1 bits, writes spk2 bits
//   k3: conv3 over all t, writes d_out (b, 8192, t) directly
// Workspace: spk1 bits 10,485,760 B + spk2 bits 2,621,440 B = 13.1 MB.

#define DECAY 0.2f
#define TH 0.5f

// -------------------------------------------------------------------------
// Kernel 1: conv1 (IC=2, 128x128 -> OC=32, 64x64), grid 32*64, block 256.
// Tile 8x8 outputs, thread owns 4oc x 2ow. Input patch staged for ALL 20 t
// (t is innermost in the input layout -> 80B contiguous per pixel).
// -------------------------------------------------------------------------
__global__ __launch_bounds__(256, 3)
void k1_conv(const float* __restrict__ in, const float* __restrict__ w1,
             const float* __restrict__ b1, uint8_t* __restrict__ sp1)
{
    __shared__ float P[20 * 612];   // [t][(ic*17+ihl)][18]: cols 0..7=E, 8..16=O
    __shared__ float wl[576];       // [ic][kh][kw][oc]
    __shared__ uint32_t bm[256];    // byte-merge scratch [oc][r][owp]

    const int tid  = threadIdx.x;
    const int b    = blockIdx.x >> 6;
    const int tile = blockIdx.x & 63;
    const int oh0  = (tile >> 3) << 3;
    const int ow0  = (tile & 7) << 3;

    // stage weights: wl[(ic*9+kh*3+kw)*32+oc] <- w1[oc][ic][kh][kw]
    for (int idx = tid; idx < 576; idx += 256) {
        int oc = idx & 31, rest = idx >> 5;        // rest = ic*9 + r9
        int ic = rest / 9, r9 = rest - ic * 9;
        wl[idx] = w1[(oc * 2 + ic) * 9 + r9];
    }
    // stage input patch for all t: 2ic x 17ih x 17iw pixels x 5 float4
    for (int idx = tid; idx < 2890; idx += 256) {
        int q = idx % 5, rest = idx / 5;
        int iwl = rest % 17, rest2 = rest / 17;
        int ihl = rest2 % 17, c = rest2 / 17;
        int ih = 2 * oh0 - 1 + ihl;
        int iw = 2 * ow0 - 1 + iwl;
        float4 v = make_float4(0.f, 0.f, 0.f, 0.f);
        if (ih >= 0 && iw >= 0)
            v = *(const float4*)&in[(((size_t)(b * 2 + c) * 128 + ih) * 128 + iw) * 20 + q * 4];
        int col = (iwl & 1) ? ((iwl - 1) >> 1) : (8 + (iwl >> 1));
        float* dst = &P[(c * 17 + ihl) * 18 + col];
        int t0 = q * 4;
        dst[(t0 + 0) * 612] = v.x;
        dst[(t0 + 1) * 612] = v.y;
        dst[(t0 + 2) * 612] = v.z;
        dst[(t0 + 3) * 612] = v.w;
    }

    const int ocg = tid >> 5, oc0 = ocg << 2;
    const int sl  = tid & 31;
    const int r   = sl >> 2;
    const int owp = sl & 3, owl = owp << 1;

    const float4 bias = *(const float4*)&b1[oc0];
    float pot[8];
    #pragma unroll
    for (int i = 0; i < 8; i++) pot[i] = 0.0f;

    __syncthreads();

    for (int t = 0; t < 20; t++) {
        float acc[8];
        #pragma unroll
        for (int i = 0; i < 8; i++) acc[i] = 0.0f;
        const float* Pt = &P[t * 612];
        #pragma unroll
        for (int ic = 0; ic < 2; ic++) {
            #pragma unroll
            for (int kh = 0; kh < 3; kh++) {
                const float* row = Pt + (ic * 17 + 2 * r + kh) * 18;
                float eA = row[owl],     eB = row[owl + 1];
                float oA = row[8 + owl], oB = row[9 + owl], oC = row[10 + owl];
                const float* wb = &wl[(ic * 9 + kh * 3) * 32 + oc0];
                float4 w0  = *(const float4*)(wb);
                float4 w1v = *(const float4*)(wb + 32);
                float4 w2v = *(const float4*)(wb + 64);
                acc[0] += w0.x * oA;  acc[1] += w0.x * oB;
                acc[2] += w0.y * oA;  acc[3] += w0.y * oB;
                acc[4] += w0.z * oA;  acc[5] += w0.z * oB;
                acc[6] += w0.w * oA;  acc[7] += w0.w * oB;
                acc[0] += w1v.x * eA; acc[1] += w1v.x * eB;
                acc[2] += w1v.y * eA; acc[3] += w1v.y * eB;
                acc[4] += w1v.z * eA; acc[5] += w1v.z * eB;
                acc[6] += w1v.w * eA; acc[7] += w1v.w * eB;
                acc[0] += w2v.x * oB; acc[1] += w2v.x * oC;
                acc[2] += w2v.y * oB; acc[3] += w2v.y * oC;
                acc[4] += w2v.z * oB; acc[5] += w2v.z * oC;
                acc[6] += w2v.w * oB; acc[7] += w2v.w * oC;
            }
        }
        // membrane update + spike bits
        #pragma unroll
        for (int k = 0; k < 4; k++) {
            float bk = ((const float*)&bias)[k];
            uint32_t v = 0;
            #pragma unroll
            for (int w = 0; w < 2; w++) {
                float conv = acc[k * 2 + w] + bk;
                float p = pot[k * 2 + w];
                float u = (p > TH) ? conv : (p * DECAY + conv);
                pot[k * 2 + w] = u;
                if (u > TH) v |= 1u << (owl + w);
            }
            ((uint8_t*)bm)[((oc0 + k) * 8 + r) * 4 + owp] = (uint8_t)v;
        }
        __syncthreads();
        {
            int oc = tid >> 3, rr = tid & 7;
            uint32_t w4 = bm[oc * 8 + rr];
            uint32_t byt = (w4 | (w4 >> 8) | (w4 >> 16) | (w4 >> 24)) & 0xFFu;
            sp1[(((t * 32 + b) * 32 + oc) * 64 + (oh0 + rr)) * 8 + (ow0 >> 3)] = (uint8_t)byt;
        }
        __syncthreads();
    }
}

// -------------------------------------------------------------------------
// Kernel 2: conv2 (IC=32, 64x64 -> OC=32, 32x32), grid 32*16, block 256.
// Tile 8x8, thread 4oc x 2ow. Per (t, ic-chunk of 8): expand spk1 bits into
// even/odd de-interleaved LDS float patch, then accumulate.
// -------------------------------------------------------------------------
__global__ __launch_bounds__(256, 3)
void k2_conv(const uint8_t* __restrict__ sp1, const float* __restrict__ w2,
             const float* __restrict__ b2, uint8_t* __restrict__ sp2)
{
    __shared__ float wl[9216];           // [ic][kh][kw][oc]
    __shared__ float P[8 * 17 * 18];
    __shared__ uint32_t bm[256];

    const int tid  = threadIdx.x;
    const int b    = blockIdx.x >> 4;
    const int tile = blockIdx.x & 15;
    const int oh0  = (tile >> 2) << 3;
    const int ow0  = (tile & 3) << 3;

    for (int idx = tid; idx < 9216; idx += 256) {
        int oc = idx & 31, rest = idx >> 5;
        int ic = rest / 9, r9 = rest - ic * 9;
        wl[idx] = w2[(oc * 32 + ic) * 9 + r9];
    }

    const int ocg = tid >> 5, oc0 = ocg << 2;
    const int sl = tid & 31, r = sl >> 2, owp = sl & 3, owl = owp << 1;
    const float4 bias = *(const float4*)&b2[oc0];
    float pot[8];
    #pragma unroll
    for (int i = 0; i < 8; i++) pot[i] = 0.0f;

    for (int t = 0; t < 20; t++) {
        float acc[8];
        #pragma unroll
        for (int i = 0; i < 8; i++) acc[i] = 0.0f;
        for (int cc = 0; cc < 4; cc++) {
            __syncthreads();
            if (tid < 136) {
                int ic = tid / 17, ihl = tid - ic * 17;
                int ih = 2 * oh0 - 1 + ihl;
                unsigned long long rowb = 0ull;
                if (ih >= 0)
                    rowb = *(const unsigned long long*)
                           &sp1[(((t * 32 + b) * 32 + (cc * 8 + ic)) * 64 + ih) * 8];
                float* dst = &P[(ic * 17 + ihl) * 18];
                #pragma unroll
                for (int iwl = 0; iwl < 17; iwl++) {
                    int iw = 2 * ow0 - 1 + iwl;
                    int col = (iwl & 1) ? ((iwl - 1) >> 1) : (8 + (iwl >> 1));
                    dst[col] = (iw >= 0 && ((rowb >> iw) & 1ull)) ? 1.0f : 0.0f;
                }
            }
            __syncthreads();
            #pragma unroll
            for (int ic = 0; ic < 8; ic++) {
                #pragma unroll
                for (int kh = 0; kh < 3; kh++) {
                    const float* row = &P[(ic * 17 + 2 * r + kh) * 18];
                    float eA = row[owl],     eB = row[owl + 1];
                    float oA = row[8 + owl], oB = row[9 + owl], oC = row[10 + owl];
                    const float* wb = &wl[((cc * 8 + ic) * 9 + kh * 3) * 32 + oc0];
                    float4 w0  = *(const float4*)(wb);
                    float4 w1v = *(const float4*)(wb + 32);
                    float4 w2v = *(const float4*)(wb + 64);
                    acc[0] += w0.x * oA;  acc[1] += w0.x * oB;
                    acc[2] += w0.y * oA;  acc[3] += w0.y * oB;
                    acc[4] += w0.z * oA;  acc[5] += w0.z * oB;
                    acc[6] += w0.w * oA;  acc[7] += w0.w * oB;
                    acc[0] += w1v.x * eA; acc[1] += w1v.x * eB;
                    acc[2] += w1v.y * eA; acc[3] += w1v.y * eB;
                    acc[4] += w1v.z * eA; acc[5] += w1v.z * eB;
                    acc[6] += w1v.w * eA; acc[7] += w1v.w * eB;
                    acc[0] += w2v.x * oB; acc[1] += w2v.x * oC;
                    acc[2] += w2v.y * oB; acc[3] += w2v.y * oC;
                    acc[4] += w2v.z * oB; acc[5] += w2v.z * oC;
                    acc[6] += w2v.w * oB; acc[7] += w2v.w * oC;
                }
            }
        }
        #pragma unroll
        for (int k = 0; k < 4; k++) {
            float bk = ((const float*)&bias)[k];
            uint32_t v = 0;
            #pragma unroll
            for (int w = 0; w < 2; w++) {
                float conv = acc[k * 2 + w] + bk;
                float p = pot[k * 2 + w];
                float u = (p > TH) ? conv : (p * DECAY + conv);
                pot[k * 2 + w] = u;
                if (u > TH) v |= 1u << (owl + w);
            }
            ((uint8_t*)bm)[((oc0 + k) * 8 + r) * 4 + owp] = (uint8_t)v;
        }
        __syncthreads();
        {
            int oc = tid >> 3, rr = tid & 7;
            uint32_t w4 = bm[oc * 8 + rr];
            uint32_t byt = (w4 | (w4 >> 8) | (w4 >> 16) | (w4 >> 24)) & 0xFFu;
            sp2[(((t * 32 + b) * 32 + oc) * 32 + (oh0 + rr)) * 4 + (ow0 >> 3)] = (uint8_t)byt;
        }
        // bm reuse protected by the cc=0 __syncthreads of the next t
    }
}

// -------------------------------------------------------------------------
// Kernel 3: conv3 (IC=32, 32x32 -> OC=32, 16x16), grid 32*8, block 256.
// Tile 8w x 4h, thread 2oc x 2ow. Spike bits for all 20 t accumulated in a
// register mask per output element; written as 5 x float4 (80B contiguous).
// -------------------------------------------------------------------------
__global__ __launch_bounds__(256, 3)
void k3_conv(const uint8_t* __restrict__ sp2, const float* __restrict__ w3,
             const float* __restrict__ b3, float* __restrict__ out)
{
    __shared__ float wl[9216];
    __shared__ float P[8 * 9 * 18];

    const int tid  = threadIdx.x;
    const int b    = blockIdx.x >> 3;
    const int tile = blockIdx.x & 7;
    const int oh0  = (tile >> 1) << 2;
    const int ow0  = (tile & 1) << 3;

    for (int idx = tid; idx < 9216; idx += 256) {
        int oc = idx & 31, rest = idx >> 5;
        int ic = rest / 9, r9 = rest - ic * 9;
        wl[idx] = w3[(oc * 32 + ic) * 9 + r9];
    }

    const int ocg = tid >> 4, oc0 = ocg << 1;
    const int sl = tid & 15, r = sl >> 2, owp = sl & 3, owl = owp << 1;
    const float2 bias = *(const float2*)&b3[oc0];
    float pot[4];
    uint32_t om[4];
    #pragma unroll
    for (int i = 0; i < 4; i++) { pot[i] = 0.0f; om[i] = 0u; }

    for (int t = 0; t < 20; t++) {
        float acc[4];
        #pragma unroll
        for (int i = 0; i < 4; i++) acc[i] = 0.0f;
        for (int cc = 0; cc < 4; cc++) {
            __syncthreads();
            if (tid < 72) {
                int ic = tid / 9, ihl = tid - ic * 9;
                int ih = 2 * oh0 - 1 + ihl;
                uint32_t rowb = 0u;
                if (ih >= 0)
                    rowb = *(const uint32_t*)
                           &sp2[(((t * 32 + b) * 32 + (cc * 8 + ic)) * 32 + ih) * 4];
                float* dst = &P[(ic * 9 + ihl) * 18];
                #pragma unroll
                for (int iwl = 0; iwl < 17; iwl++) {
                    int iw = 2 * ow0 - 1 + iwl;
                    int col = (iwl & 1) ? ((iwl - 1) >> 1) : (8 + (iwl >> 1));
                    dst[col] = (iw >= 0 && ((rowb >> iw) & 1u)) ? 1.0f : 0.0f;
                }
            }
            __syncthreads();
            #pragma unroll
            for (int ic = 0; ic < 8; ic++) {
                #pragma unroll
                for (int kh = 0; kh < 3; kh++) {
                    const float* row = &P[(ic * 9 + 2 * r + kh) * 18];
                    float eA = row[owl],     eB = row[owl + 1];
                    float oA = row[8 + owl], oB = row[9 + owl], oC = row[10 + owl];
                    const float* wb = &wl[((cc * 8 + ic) * 9 + kh * 3) * 32 + oc0];
                    float2 w0  = *(const float2*)(wb);
                    float2 w1v = *(const float2*)(wb + 32);
                    float2 w2v = *(const float2*)(wb + 64);
                    acc[0] += w0.x * oA;  acc[1] += w0.x * oB;
                    acc[2] += w0.y * oA;  acc[3] += w0.y * oB;
                    acc[0] += w1v.x * eA; acc[1] += w1v.x * eB;
                    acc[2] += w1v.y * eA; acc[3] += w1v.y * eB;
                    acc[0] += w2v.x * oB; acc[1] += w2v.x * oC;
                    acc[2] += w2v.y * oB; acc[3] += w2v.y * oC;
                }
            }
        }
        #pragma unroll
        for (int k = 0; k < 2; k++) {
            float bk = (k == 0) ? bias.x : bias.y;
            #pragma unroll
            for (int w = 0; w < 2; w++) {
                float conv = acc[k * 2 + w] + bk;
                float p = pot[k * 2 + w];
                float u = (p > TH) ? conv : (p * DECAY + conv);
                pot[k * 2 + w] = u;
                if (u > TH) om[k * 2 + w] |= 1u << t;
            }
        }
    }

    #pragma unroll
    for (int k = 0; k < 2; k++) {
        #pragma unroll
        for (int w = 0; w < 2; w++) {
            int oc = oc0 + k;
            int oh = oh0 + r, ow = ow0 + owl + w;
            int i = (oc << 8) + (oh << 4) + ow;
            float* dst = &out[((size_t)b * 8192 + i) * 20];
            uint32_t m = om[k * 2 + w];
            #pragma unroll
            for (int q = 0; q < 5; q++) {
                float4 v;
                v.x = ((m >> (q * 4 + 0)) & 1u) ? 1.0f : 0.0f;
                v.y = ((m >> (q * 4 + 1)) & 1u) ? 1.0f : 0.0f;
                v.z = ((m >> (q * 4 + 2)) & 1u) ? 1.0f : 0.0f;
                v.w = ((m >> (q * 4 + 3)) & 1u) ? 1.0f : 0.0f;
                *(float4*)&dst[q * 4] = v;
            }
        }
    }
}

extern "C" void kernel_launch(void* const* d_in, const int* in_sizes, int n_in,
                              void* d_out, int out_size, void* d_ws, size_t ws_size,
                              hipStream_t stream)
{
    (void)in_sizes; (void)n_in; (void)out_size; (void)ws_size;
    const float* in = (const float*)d_in[0];
    const float* w1 = (const float*)d_in[1];
    const float* b1 = (const float*)d_in[2];
    const float* w2 = (const float*)d_in[3];
    const float* b2 = (const float*)d_in[4];
    const float* w3 = (const float*)d_in[5];
    const float* b3 = (const float*)d_in[6];

    uint8_t* sp1 = (uint8_t*)d_ws;                      // 20*32*32*64*8 = 10,485,760 B
    uint8_t* sp2 = sp1 + (size_t)20 * 32 * 32 * 64 * 8; // 20*32*32*32*4 =  2,621,440 B

    k1_conv<<<32 * 64, 256, 0, stream>>>(in, w1, b1, sp1);
    k2_conv<<<32 * 16, 256, 0, stream>>>(sp1, w2, b2, sp2);
    k3_conv<<<32 * 8, 256, 0, stream>>>(sp2, w3, b3, (float*)d_out);
}